// Round 4
// baseline (1090.852 us; speedup 1.0000x reference)
//
#include <hip/hip_runtime.h>
#include <math.h>

// Problem constants (fixed by the reference)
#define BN   8
#define NN   1024
#define FIN  256
#define HIDN 128
#define KTOP 513          // int(1024*0.5)+1
#define NITER 20          // opt_epochs in setup_inputs
#define EPS_S 0.01f
#define INV_EPS 100.0f
#define LOG_MU (-6.9314718055994531f)   // -log(1024)
#define PARTS 1024

typedef __attribute__((ext_vector_type(8))) short bfrag8;   // 8 bf16 (4 VGPR)
typedef __attribute__((ext_vector_type(4))) float facc4;    // MFMA accumulator

#define GLOAD16(g, l) __builtin_amdgcn_global_load_lds( \
    (const __attribute__((address_space(1))) unsigned int*)(g), \
    (__attribute__((address_space(3))) unsigned int*)(l), 16, 0, 0)

static __device__ __forceinline__ float wred_sum(float s) {
#pragma unroll
  for (int o = 32; o > 0; o >>= 1) s += __shfl_xor(s, o);
  return s;
}
static __device__ __forceinline__ float wred_max(float s) {
#pragma unroll
  for (int o = 32; o > 0; o >>= 1) s = fmaxf(s, __shfl_xor(s, o));
  return s;
}
static __device__ __forceinline__ unsigned short f2b(float f) {
  unsigned int u = __float_as_uint(f);
  u += 0x7fff + ((u >> 16) & 1);      // RNE
  return (unsigned short)(u >> 16);
}
static __device__ __forceinline__ float b2f(unsigned short h) {
  return __uint_as_float((unsigned int)h << 16);
}

// ---- rowstats (4 rows/block): d = rsqrt(max(rowsum+1,1)), rmask; opt bf16 --
template<int WRBF>
__global__ __launch_bounds__(256) void k_rowstats4(const float* __restrict__ adj,
                                                   float* __restrict__ dv,
                                                   float* __restrict__ rm,
                                                   unsigned short* __restrict__ abf) {
  int r0 = blockIdx.x << 2;
  int t = threadIdx.x, lane = t & 63, wv = t >> 6;
  __shared__ float sm[4][4];
#pragma unroll
  for (int r = 0; r < 4; ++r) {
    float4 v = ((const float4*)(adj + (long)(r0 + r) * NN))[t];
    if (WRBF) {
      ushort4 h; h.x = f2b(v.x); h.y = f2b(v.y); h.z = f2b(v.z); h.w = f2b(v.w);
      *(ushort4*)(abf + (long)(r0 + r) * NN + t * 4) = h;
    }
    float s = (v.x + v.y) + (v.z + v.w);
    s = wred_sum(s);
    if (lane == 0) sm[wv][r] = s;
  }
  __syncthreads();
  if (t < 4) {
    float tot = sm[0][t] + sm[1][t] + sm[2][t] + sm[3][t];
    dv[r0 + t] = rsqrtf(fmaxf(tot + 1.0f, 1.0f));
    rm[r0 + t] = tot > 0.0f ? 1.0f : 0.0f;
  }
}

// ---- fp32 X -> bf16 hi + bf16 lo (split for 3-product MFMA) ---------------
__global__ __launch_bounds__(256) void k_split2(const float* __restrict__ X,
                                                unsigned short* __restrict__ Xh,
                                                unsigned short* __restrict__ Xl) {
  long i = ((long)blockIdx.x * 256 + threadIdx.x) * 4;
  float4 v = *(const float4*)(X + i);
  ushort4 h, l;
  h.x = f2b(v.x); l.x = f2b(v.x - b2f(h.x));
  h.y = f2b(v.y); l.y = f2b(v.y - b2f(h.y));
  h.z = f2b(v.z); l.z = f2b(v.z - b2f(h.z));
  h.w = f2b(v.w); l.w = f2b(v.w - b2f(h.w));
  *(ushort4*)(Xh + i) = h;
  *(ushort4*)(Xl + i) = l;
}

// ---------------- fp32 [R][C] -> bf16 [C][R] transpose ----------------------
__global__ __launch_bounds__(256) void k_transp(const float* __restrict__ X,
                                                unsigned short* __restrict__ Xt,
                                                int R, int C) {
  __shared__ float tile[64][65];
  long bb = blockIdx.z;
  const float* Xb = X + bb * (long)R * C;
  unsigned short* Xtb = Xt + bb * (long)R * C;
  int r0 = blockIdx.y * 64, c0 = blockIdx.x * 64;
  int t = threadIdx.x;
  int tr = t >> 4, tc4 = (t & 15) * 4;
#pragma unroll
  for (int p = 0; p < 4; ++p) {
    float4 v = *(const float4*)(Xb + (long)(r0 + tr + p * 16) * C + c0 + tc4);
    tile[tr + p * 16][tc4 + 0] = v.x; tile[tr + p * 16][tc4 + 1] = v.y;
    tile[tr + p * 16][tc4 + 2] = v.z; tile[tr + p * 16][tc4 + 3] = v.w;
  }
  __syncthreads();
  int jj = t >> 2, i0 = (t & 3) * 16;
  unsigned short* orow = Xtb + (long)(c0 + jj) * R + r0 + i0;
#pragma unroll
  for (int q = 0; q < 16; ++q) orow[q] = f2b(tile[i0 + q][jj]);
}

// ---------------- fp32 [NN][NN] -> fp32 [NN][NN] transpose ------------------
__global__ __launch_bounds__(256) void k_transpf(const float* __restrict__ X,
                                                 float* __restrict__ Xt) {
  __shared__ float tile[64][65];
  long bb = blockIdx.z;
  const float* Xb = X + bb * (long)NN * NN;
  float* Xtb = Xt + bb * (long)NN * NN;
  int r0 = blockIdx.y * 64, c0 = blockIdx.x * 64;
  int t = threadIdx.x;
  int tr = t >> 4, tc4 = (t & 15) * 4;
#pragma unroll
  for (int p = 0; p < 4; ++p) {
    float4 v = *(const float4*)(Xb + (long)(r0 + tr + p * 16) * NN + c0 + tc4);
    tile[tr + p * 16][tc4 + 0] = v.x; tile[tr + p * 16][tc4 + 1] = v.y;
    tile[tr + p * 16][tc4 + 2] = v.z; tile[tr + p * 16][tc4 + 3] = v.w;
  }
  __syncthreads();
  int jj = t >> 2, i0 = (t & 3) * 16;
  float* orow = Xtb + (long)(c0 + jj) * NN + r0 + i0;
#pragma unroll
  for (int q = 0; q < 16; q += 4) {
    float4 w4 = { tile[i0 + q][jj], tile[i0 + q + 1][jj],
                  tile[i0 + q + 2][jj], tile[i0 + q + 3][jj] };
    *(float4*)(orow + q) = w4;
  }
}

// ---------------- bf16 NT MFMA GEMM: C[m,n] = sum_k A[m,k]*B[n,k] -----------
template<int WF32, int WBF>
__global__ __launch_bounds__(256) void k_mfma_nt(
    const unsigned short* __restrict__ A, const unsigned short* __restrict__ B,
    float* __restrict__ Cf, unsigned short* __restrict__ Cb,
    int K, int ldA, int ldB, int ldC, long sA, long sB, long sC) {
  __shared__ unsigned short As[128 * 32];
  __shared__ unsigned short Bs[128 * 32];
  int bz = blockIdx.z;
  A += bz * sA; B += bz * sB;
  int m0 = blockIdx.y * 128, n0 = blockIdx.x * 128;
  int tid = threadIdx.x, lane = tid & 63, w = tid >> 6;
  int wr = w >> 1, wc = w & 1;
  facc4 acc[4][4];
#pragma unroll
  for (int i = 0; i < 4; ++i)
#pragma unroll
    for (int j = 0; j < 4; ++j)
#pragma unroll
      for (int q = 0; q < 4; ++q) acc[i][j][q] = 0.f;

  int rA0 = w * 16 + (lane >> 2);   // staging row within 64-row half
  int kslot = lane & 3;             // 16B slot within 64B row

  for (int k0 = 0; k0 < K; k0 += 32) {
#pragma unroll
    for (int i = 0; i < 2; ++i) {
      int row = i * 64 + rA0;
      int ks = (kslot ^ (row & 3)) << 3;   // pre-swizzled global source
      GLOAD16(A + (long)(m0 + row) * ldA + k0 + ks, As + (i * 64 + w * 16) * 32);
      GLOAD16(B + (long)(n0 + row) * ldB + k0 + ks, Bs + (i * 64 + w * 16) * 32);
    }
    __syncthreads();
    bfrag8 af[4], bfr[4];
#pragma unroll
    for (int mi = 0; mi < 4; ++mi) {
      int row = wr * 64 + mi * 16 + (lane & 15);
      int sl = (((lane >> 4) ^ (row & 3)) << 3);   // swizzled read
      af[mi] = *(const bfrag8*)(As + row * 32 + sl);
    }
#pragma unroll
    for (int ni = 0; ni < 4; ++ni) {
      int row = wc * 64 + ni * 16 + (lane & 15);
      int sl = (((lane >> 4) ^ (row & 3)) << 3);
      bfr[ni] = *(const bfrag8*)(Bs + row * 32 + sl);
    }
#pragma unroll
    for (int mi = 0; mi < 4; ++mi)
#pragma unroll
      for (int ni = 0; ni < 4; ++ni)
        acc[mi][ni] = __builtin_amdgcn_mfma_f32_16x16x32_bf16(
            af[mi], bfr[ni], acc[mi][ni], 0, 0, 0);
    __syncthreads();
  }
  if (WF32) Cf += bz * sC;
  if (WBF) Cb += bz * sC;
#pragma unroll
  for (int mi = 0; mi < 4; ++mi) {
    int rowb = m0 + wr * 64 + mi * 16 + ((lane >> 4) << 2);
#pragma unroll
    for (int ni = 0; ni < 4; ++ni) {
      int col = n0 + wc * 64 + ni * 16 + (lane & 15);
#pragma unroll
      for (int q = 0; q < 4; ++q) {
        long off = (long)(rowb + q) * ldC + col;
        float v = acc[mi][ni][q];
        if (WF32) Cf[off] = v;
        if (WBF) Cb[off] = f2b(v);
      }
    }
  }
}

// ---- split-bf16 3-product NT MFMA Gram: C = xx_m + yy_n - 2*sum A[m,:]B[n,:]
__global__ __launch_bounds__(256) void k_mfma_gram(
    const unsigned short* __restrict__ Ah, const unsigned short* __restrict__ Al,
    const unsigned short* __restrict__ Bh, const unsigned short* __restrict__ Bl,
    const float* __restrict__ xx, const float* __restrict__ yy,
    float* __restrict__ Cf) {
  __shared__ unsigned short AsH[128 * 32], AsL[128 * 32];
  __shared__ unsigned short BsH[128 * 32], BsL[128 * 32];
  int bz = blockIdx.z;
  long boff = (long)bz * NN * FIN;
  Ah += boff; Al += boff; Bh += boff; Bl += boff;
  const float* xxb = xx + (bz << 10);
  const float* yyb = yy + (bz << 10);
  int m0 = blockIdx.y * 128, n0 = blockIdx.x * 128;
  int tid = threadIdx.x, lane = tid & 63, w = tid >> 6;
  int wr = w >> 1, wc = w & 1;
  facc4 acc[4][4];
#pragma unroll
  for (int i = 0; i < 4; ++i)
#pragma unroll
    for (int j = 0; j < 4; ++j)
#pragma unroll
      for (int q = 0; q < 4; ++q) acc[i][j][q] = 0.f;

  int rA0 = w * 16 + (lane >> 2);
  int kslot = lane & 3;

  for (int k0 = 0; k0 < FIN; k0 += 32) {
#pragma unroll
    for (int i = 0; i < 2; ++i) {
      int row = i * 64 + rA0;
      int ks = (kslot ^ (row & 3)) << 3;
      long ga = (long)(m0 + row) * FIN + k0 + ks;
      long gb = (long)(n0 + row) * FIN + k0 + ks;
      int ld = (i * 64 + w * 16) * 32;
      GLOAD16(Ah + ga, AsH + ld);
      GLOAD16(Al + ga, AsL + ld);
      GLOAD16(Bh + gb, BsH + ld);
      GLOAD16(Bl + gb, BsL + ld);
    }
    __syncthreads();
    bfrag8 afh[4], afl[4], bfh[4], bfl[4];
#pragma unroll
    for (int mi = 0; mi < 4; ++mi) {
      int row = wr * 64 + mi * 16 + (lane & 15);
      int sl = (((lane >> 4) ^ (row & 3)) << 3);
      afh[mi] = *(const bfrag8*)(AsH + row * 32 + sl);
      afl[mi] = *(const bfrag8*)(AsL + row * 32 + sl);
    }
#pragma unroll
    for (int ni = 0; ni < 4; ++ni) {
      int row = wc * 64 + ni * 16 + (lane & 15);
      int sl = (((lane >> 4) ^ (row & 3)) << 3);
      bfh[ni] = *(const bfrag8*)(BsH + row * 32 + sl);
      bfl[ni] = *(const bfrag8*)(BsL + row * 32 + sl);
    }
#pragma unroll
    for (int mi = 0; mi < 4; ++mi)
#pragma unroll
      for (int ni = 0; ni < 4; ++ni) {
        acc[mi][ni] = __builtin_amdgcn_mfma_f32_16x16x32_bf16(
            afh[mi], bfh[ni], acc[mi][ni], 0, 0, 0);
        acc[mi][ni] = __builtin_amdgcn_mfma_f32_16x16x32_bf16(
            afh[mi], bfl[ni], acc[mi][ni], 0, 0, 0);
        acc[mi][ni] = __builtin_amdgcn_mfma_f32_16x16x32_bf16(
            afl[mi], bfh[ni], acc[mi][ni], 0, 0, 0);
      }
    __syncthreads();
  }
  Cf += (long)bz * NN * NN;
#pragma unroll
  for (int mi = 0; mi < 4; ++mi) {
    int rowb = m0 + wr * 64 + mi * 16 + ((lane >> 4) << 2);
#pragma unroll
    for (int ni = 0; ni < 4; ++ni) {
      int col = n0 + wc * 64 + ni * 16 + (lane & 15);
      float yv = yyb[col];
#pragma unroll
      for (int q = 0; q < 4; ++q)
        Cf[(long)(rowb + q) * NN + col] = xxb[rowb + q] + yv - 2.f * acc[mi][ni][q];
    }
  }
}

// ---------------- s0 = cx @ Watt  (per-row dot, HID=128) --------------------
__global__ __launch_bounds__(256) void k_rowdot(const float* __restrict__ X,
                                                const float* __restrict__ w,
                                                float* __restrict__ out) {
  int t = threadIdx.x; int lane = t & 63; int wv = t >> 6;
  int row = blockIdx.x * 4 + wv;
  const float* xr = X + (long)row * HIDN;
  float s = xr[lane] * w[lane] + xr[lane + 64] * w[lane + 64];
  s = wred_sum(s);
  if (lane == 0) out[row] = s;
}

// ---- alpha (4 rows/block) = sigmoid((gcn_norm(adj) @ s0 + batt)^2) ---------
__global__ __launch_bounds__(256) void k_alpha4(const float* __restrict__ adj,
                                                const float* __restrict__ dv,
                                                const float* __restrict__ s0,
                                                const float* __restrict__ batt,
                                                float* __restrict__ alpha) {
  int r0 = blockIdx.x << 2; int b = r0 >> 10; int i0 = r0 & (NN - 1);
  int t = threadIdx.x, lane = t & 63, wv = t >> 6;
  float4 d4 = ((const float4*)(dv + (b << 10)))[t];
  float4 s4 = ((const float4*)(s0 + (b << 10)))[t];
  float w4[4];
  w4[0] = d4.x * s4.x; w4[1] = d4.y * s4.y; w4[2] = d4.z * s4.z; w4[3] = d4.w * s4.w;
  __shared__ float sm[4][4];
#pragma unroll
  for (int r = 0; r < 4; ++r) {
    float4 a4 = ((const float4*)(adj + (long)(r0 + r) * NN))[t];
    float dot = a4.x * w4[0] + a4.y * w4[1] + a4.z * w4[2] + a4.w * w4[3];
    int i = i0 + r;
    if ((i >> 2) == t) dot += w4[i & 3];   // +I diagonal
    dot = wred_sum(dot);
    if (lane == 0) sm[wv][r] = dot;
  }
  __syncthreads();
  if (t < 4) {
    float dot = sm[0][t] + sm[1][t] + sm[2][t] + sm[3][t];
    float tt = dv[r0 + t] * dot + batt[0];
    alpha[r0 + t] = 1.f / (1.f + __expf(-tt * tt));
  }
}

// ---------------- per-batch k-th largest via bitonic sort -------------------
__global__ __launch_bounds__(512) void k_topk(const float* __restrict__ alpha,
                                              float* __restrict__ cut) {
  __shared__ float smv[NN];
  int b = blockIdx.x; int t = threadIdx.x;
  smv[t] = alpha[(b << 10) + t];
  smv[t + 512] = alpha[(b << 10) + t + 512];
  __syncthreads();
  for (int k2 = 2; k2 <= NN; k2 <<= 1) {
    for (int j2 = k2 >> 1; j2 > 0; j2 >>= 1) {
      int i = ((t / j2) * (j2 << 1)) + (t % j2);
      int ixj = i + j2;
      bool up = ((i & k2) == 0);
      float a = smv[i], c = smv[ixj];
      if ((a > c) == up) { smv[i] = c; smv[ixj] = a; }
      __syncthreads();
    }
  }
  if (t == 0) cut[b] = smv[NN - KTOP];   // ascending sort: 513th largest
}

// ---- S build (4 rows/block): rmask_i d_i d_j (adj+I) gate_j, row-L1 norm ---
__global__ __launch_bounds__(256) void k_sbuild4(const float* __restrict__ adj,
                                                 const float* __restrict__ dv,
                                                 const float* __restrict__ rm,
                                                 const float* __restrict__ alpha,
                                                 const float* __restrict__ cut,
                                                 float* __restrict__ S) {
  int r0 = blockIdx.x << 2; int b = r0 >> 10; int i0 = r0 & (NN - 1);
  int t = threadIdx.x, lane = t & 63, wv = t >> 6;
  float cb = cut[b];
  float4 d4 = ((const float4*)(dv + (b << 10)))[t];
  float4 al4 = ((const float4*)(alpha + (b << 10)))[t];
  float4 dg;
  dg.x = d4.x * fmaxf(al4.x + 1e-7f - cb, 0.f);
  dg.y = d4.y * fmaxf(al4.y + 1e-7f - cb, 0.f);
  dg.z = d4.z * fmaxf(al4.z + 1e-7f - cb, 0.f);
  dg.w = d4.w * fmaxf(al4.w + 1e-7f - cb, 0.f);
  __shared__ float sm[4][4];
  __shared__ float sinv[4];
  float4 vals[4];
#pragma unroll
  for (int r = 0; r < 4; ++r) {
    float di = dv[r0 + r] * rm[r0 + r];
    float4 a4 = ((const float4*)(adj + (long)(r0 + r) * NN))[t];
    int i = i0 + r;
    if ((i >> 2) == t) ((float*)&a4)[i & 3] += 1.f;   // +I diagonal
    vals[r].x = di * dg.x * a4.x; vals[r].y = di * dg.y * a4.y;
    vals[r].z = di * dg.z * a4.z; vals[r].w = di * dg.w * a4.w;
    float s = (fabsf(vals[r].x) + fabsf(vals[r].y)) +
              (fabsf(vals[r].z) + fabsf(vals[r].w));
    s = wred_sum(s);
    if (lane == 0) sm[wv][r] = s;
  }
  __syncthreads();
  if (t < 4) sinv[t] = 1.f / fmaxf(sm[0][t] + sm[1][t] + sm[2][t] + sm[3][t], 1e-12f);
  __syncthreads();
#pragma unroll
  for (int r = 0; r < 4; ++r) {
    float inv = sinv[r];
    float4 o; o.x = vals[r].x * inv; o.y = vals[r].y * inv;
    o.z = vals[r].z * inv; o.w = vals[r].w * inv;
    ((float4*)(S + (long)(r0 + r) * NN))[t] = o;
  }
}

// ---------------- generic fp32 tiled GEMM (small matmuls) -------------------
template<int TA, int TB, int GCN, int EPI>
__global__ __launch_bounds__(256) void k_gemm(
    const float* __restrict__ A, const float* __restrict__ Bm, float* __restrict__ Cm,
    int M, int Nn, int K, long sA, long sB, long sC,
    const float* __restrict__ dv, const float* __restrict__ bias, int relu,
    const float* __restrict__ xx, const float* __restrict__ yy) {
  __shared__ float As[8][132];
  __shared__ float Bs[8][132];
  int b = blockIdx.z;
  A += (long)b * sA; Bm += (long)b * sB; Cm += (long)b * sC;
  const float* dvb = GCN ? (dv + (long)b * NN) : nullptr;
  int m0 = blockIdx.y * 128, n0 = blockIdx.x * 128;
  int tid = threadIdx.x;
  int tx = tid & 15, ty = tid >> 4;
  float acc[8][8];
#pragma unroll
  for (int i = 0; i < 8; i++)
#pragma unroll
    for (int j = 0; j < 8; j++) acc[i][j] = 0.f;

  float drow = 0.f;
  if (GCN) drow = dvb[m0 + (tid >> 1)];

  for (int k0 = 0; k0 < K; k0 += 8) {
    if (TA == 0) {
      int r = tid >> 1, c4 = (tid & 1) * 4;
      float4 av = *(const float4*)(A + (long)(m0 + r) * K + k0 + c4);
      float a4[4] = {av.x, av.y, av.z, av.w};
      if (GCN) {
#pragma unroll
        for (int q = 0; q < 4; ++q) {
          int gj = k0 + c4 + q;
          float val = a4[q] + ((m0 + r) == gj ? 1.f : 0.f);
          a4[q] = drow * dvb[gj] * val;
        }
      }
      As[c4 + 0][r] = a4[0]; As[c4 + 1][r] = a4[1];
      As[c4 + 2][r] = a4[2]; As[c4 + 3][r] = a4[3];
    } else {
      int kr = tid >> 5, c4 = (tid & 31) * 4;
      float4 av = *(const float4*)(A + (long)(k0 + kr) * M + m0 + c4);
      *(float4*)&As[kr][c4] = av;
    }
    if (TB == 0) {
      int kr = tid >> 5, c4 = (tid & 31) * 4;
      float4 bv = *(const float4*)(Bm + (long)(k0 + kr) * Nn + n0 + c4);
      *(float4*)&Bs[kr][c4] = bv;
    } else {
      int r = tid >> 1, c4 = (tid & 1) * 4;
      float4 bv = *(const float4*)(Bm + (long)(n0 + r) * K + k0 + c4);
      Bs[c4 + 0][r] = bv.x; Bs[c4 + 1][r] = bv.y;
      Bs[c4 + 2][r] = bv.z; Bs[c4 + 3][r] = bv.w;
    }
    __syncthreads();
#pragma unroll
    for (int k = 0; k < 8; ++k) {
      float av[8], bv[8];
      *(float4*)&av[0] = *(const float4*)&As[k][ty * 8];
      *(float4*)&av[4] = *(const float4*)&As[k][ty * 8 + 4];
      *(float4*)&bv[0] = *(const float4*)&Bs[k][tx * 8];
      *(float4*)&bv[4] = *(const float4*)&Bs[k][tx * 8 + 4];
#pragma unroll
      for (int i = 0; i < 8; i++)
#pragma unroll
        for (int j = 0; j < 8; j++)
          acc[i][j] = fmaf(av[i], bv[j], acc[i][j]);
    }
    __syncthreads();
  }
#pragma unroll
  for (int i = 0; i < 8; ++i) {
    int m = m0 + ty * 8 + i;
    float* crow = Cm + (long)m * Nn + n0 + tx * 8;
    float outv[8];
#pragma unroll
    for (int j = 0; j < 8; ++j) {
      float vv = acc[i][j];
      if (EPI == 1) { vv += bias[n0 + tx * 8 + j]; if (relu) vv = fmaxf(vv, 0.f); }
      outv[j] = vv;
    }
    *(float4*)&crow[0] = *(float4*)&outv[0];
    *(float4*)&crow[4] = *(float4*)&outv[4];
  }
}

// ---------------- K-split fp32 GEMM (TA=0,TB=0), partials out ---------------
template<int GCN>
__global__ __launch_bounds__(256) void k_gemm_ks(
    const float* __restrict__ A, const float* __restrict__ Bm, float* __restrict__ P,
    int M, int Nn, int K, int KS, long sA, long sB,
    const float* __restrict__ dv) {
  __shared__ float As[8][132];
  __shared__ float Bs[8][132];
  int z = blockIdx.z;
  int b = z / KS, ks = z % KS;
  int KC = K / KS;
  A += (long)b * sA; Bm += (long)b * sB;
  const float* dvb = GCN ? (dv + (long)b * NN) : nullptr;
  int m0 = blockIdx.y * 128, n0 = blockIdx.x * 128;
  int tid = threadIdx.x;
  int tx = tid & 15, ty = tid >> 4;
  float acc[8][8];
#pragma unroll
  for (int i = 0; i < 8; i++)
#pragma unroll
    for (int j = 0; j < 8; j++) acc[i][j] = 0.f;

  float drow = 0.f;
  if (GCN) drow = dvb[m0 + (tid >> 1)];

  for (int k0 = ks * KC; k0 < ks * KC + KC; k0 += 8) {
    {
      int r = tid >> 1, c4 = (tid & 1) * 4;
      float4 av = *(const float4*)(A + (long)(m0 + r) * K + k0 + c4);
      float a4[4] = {av.x, av.y, av.z, av.w};
      if (GCN) {
#pragma unroll
        for (int q = 0; q < 4; ++q) {
          int gj = k0 + c4 + q;
          float val = a4[q] + ((m0 + r) == gj ? 1.f : 0.f);
          a4[q] = drow * dvb[gj] * val;
        }
      }
      As[c4 + 0][r] = a4[0]; As[c4 + 1][r] = a4[1];
      As[c4 + 2][r] = a4[2]; As[c4 + 3][r] = a4[3];
    }
    {
      int kr = tid >> 5, c4 = (tid & 31) * 4;
      float4 bv = *(const float4*)(Bm + (long)(k0 + kr) * Nn + n0 + c4);
      *(float4*)&Bs[kr][c4] = bv;
    }
    __syncthreads();
#pragma unroll
    for (int k = 0; k < 8; ++k) {
      float av[8], bv[8];
      *(float4*)&av[0] = *(const float4*)&As[k][ty * 8];
      *(float4*)&av[4] = *(const float4*)&As[k][ty * 8 + 4];
      *(float4*)&bv[0] = *(const float4*)&Bs[k][tx * 8];
      *(float4*)&bv[4] = *(const float4*)&Bs[k][tx * 8 + 4];
#pragma unroll
      for (int i = 0; i < 8; i++)
#pragma unroll
        for (int j = 0; j < 8; j++)
          acc[i][j] = fmaf(av[i], bv[j], acc[i][j]);
    }
    __syncthreads();
  }
  float* Pz = P + (long)z * M * Nn;
#pragma unroll
  for (int i = 0; i < 8; ++i) {
    int m = m0 + ty * 8 + i;
    float* prow = Pz + (long)m * Nn + n0 + tx * 8;
    *(float4*)&prow[0] = *(float4*)&acc[i][0];
    *(float4*)&prow[4] = *(float4*)&acc[i][4];
  }
}

// ---------------- reduce K-split partials (+bias, +relu) --------------------
template<int RELU, int BIAS>
__global__ __launch_bounds__(256) void k_red_bias(
    const float* __restrict__ P, const float* __restrict__ bias,
    float* __restrict__ out, int Nn, int KS, long chunk) {
  long u = ((long)blockIdx.x * 256 + threadIdx.x) * 4;
  long b = u / chunk; long rem = u % chunk;
  const float* p = P + b * KS * chunk + rem;
  float4 s = *(const float4*)p;
  for (int k = 1; k < KS; ++k) {
    float4 q = *(const float4*)(p + (long)k * chunk);
    s.x += q.x; s.y += q.y; s.z += q.z; s.w += q.w;
  }
  if (BIAS) {
    int n = (int)(rem % Nn);
    s.x += bias[n]; s.y += bias[n + 1]; s.z += bias[n + 2]; s.w += bias[n + 3];
  }
  if (RELU) {
    s.x = fmaxf(s.x, 0.f); s.y = fmaxf(s.y, 0.f);
    s.z = fmaxf(s.z, 0.f); s.w = fmaxf(s.w, 0.f);
  }
  *(float4*)(out + u) = s;
}

// ---------------- column mean over nodes ------------------------------------
__global__ __launch_bounds__(256) void k_colmean(const float* __restrict__ X, int Fd,
                                                 float* __restrict__ out) {
  int nb = Fd >> 6;
  int b = blockIdx.x / nb; int f0 = (blockIdx.x % nb) << 6;
  int t = threadIdx.x;
  int f = f0 + (t & 63); int rc = t >> 6;
  const float* xb = X + (long)b * NN * Fd;
  float s = 0.f;
  for (int i = rc * 256; i < rc * 256 + 256; ++i) s += xb[(long)i * Fd + f];
  __shared__ float sm[256];
  sm[t] = s; __syncthreads();
  if (t < 64) out[b * Fd + f] = (sm[t] + sm[t + 64] + sm[t + 128] + sm[t + 192]) * (1.f / NN);
}

// ---------------- squared row norms -----------------------------------------
__global__ __launch_bounds__(256) void k_sqnorm(const float* __restrict__ X, int Fd,
                                                float* __restrict__ out) {
  int t = threadIdx.x; int lane = t & 63; int wv = t >> 6;
  int row = blockIdx.x * 4 + wv;
  const float* xr = X + (long)row * Fd;
  float s = 0.f;
  for (int f = lane; f < Fd; f += 64) { float v = xr[f]; s = fmaf(v, v, s); }
  s = wred_sum(s);
  if (lane == 0) out[row] = s;
}

// ---- Sinkhorn pass, 8 rows/block; LOSS variant fuses final loss ------------
// out_i = eps*(log_mu - LSE_j((vin_j - M_ij)/eps)); row pass on C, col on C^T.
template<int LOSS>
__global__ __launch_bounds__(256) void k_sink8(const float* __restrict__ Mb,
                                               const float* __restrict__ vin,
                                               float* __restrict__ uout,
                                               float* __restrict__ part) {
  int r0 = blockIdx.x << 3; int b = r0 >> 10;
  int t = threadIdx.x, lane = t & 63, wv = t >> 6;
  __shared__ float smm[4][8], sms[4][8], smd[4][8], lred[8];
  float4 v4 = ((const float4*)(vin + (b << 10)))[t];
  float4 c[8];
#pragma unroll
  for (int r = 0; r < 8; ++r)
    c[r] = ((const float4*)(Mb + (long)(r0 + r) * NN))[t];
  float4 a[8];
#pragma unroll
  for (int r = 0; r < 8; ++r) {
    a[r].x = (v4.x - c[r].x) * INV_EPS;
    a[r].y = (v4.y - c[r].y) * INV_EPS;
    a[r].z = (v4.z - c[r].z) * INV_EPS;
    a[r].w = (v4.w - c[r].w) * INV_EPS;
    float mx = fmaxf(fmaxf(a[r].x, a[r].y), fmaxf(a[r].z, a[r].w));
    mx = wred_max(mx);
    if (lane == 0) smm[wv][r] = mx;
  }
  __syncthreads();
#pragma unroll
  for (int r = 0; r < 8; ++r) {
    float M2 = fmaxf(fmaxf(smm[0][r], smm[1][r]), fmaxf(smm[2][r], smm[3][r]));
    float e0 = __expf(a[r].x - M2), e1 = __expf(a[r].y - M2);
    float e2 = __expf(a[r].z - M2), e3 = __expf(a[r].w - M2);
    float s = (e0 + e1) + (e2 + e3);
    float d = 0.f;
    if (LOSS) d = e0 * c[r].x + e1 * c[r].y + e2 * c[r].z + e3 * c[r].w;
    s = wred_sum(s);
    if (LOSS) d = wred_sum(d);
    if (lane == 0) { sms[wv][r] = s; if (LOSS) smd[wv][r] = d; }
  }
  __syncthreads();
  if (t < 8) {
    int r = t;
    float M2 = fmaxf(fmaxf(smm[0][r], smm[1][r]), fmaxf(smm[2][r], smm[3][r]));
    float tot = sms[0][r] + sms[1][r] + sms[2][r] + sms[3][r];
    uout[r0 + r] = EPS_S * (LOG_MU - (M2 + __logf(tot)));
    if (LOSS)
      lred[r] = (smd[0][r] + smd[1][r] + smd[2][r] + smd[3][r]) / tot;
  }
  if (LOSS) {
    __syncthreads();
    if (t == 0) {
      float ls = 0.f;
#pragma unroll
      for (int r = 0; r < 8; ++r) ls += lred[r];
      part[blockIdx.x] = ls * (1.0f / 1024.0f);   // * exp(LOG_NU)
    }
  }
}

__global__ __launch_bounds__(256) void k_psum(const float* __restrict__ part,
                                              float* __restrict__ out) {
  float s = 0.f;
  for (int i = threadIdx.x; i < PARTS; i += 256) s += part[i];
  s = wred_sum(s);
  __shared__ float sm[4];
  if ((threadIdx.x & 63) == 0) sm[threadIdx.x >> 6] = s;
  __syncthreads();
  if (threadIdx.x == 0) out[0] = sm[0] + sm[1] + sm[2] + sm[3];
}

extern "C" void kernel_launch(void* const* d_in, const int* in_sizes, int n_in,
                              void* d_out, int out_size, void* d_ws, size_t ws_size,
                              hipStream_t stream) {
  const float* x    = (const float*)d_in[0];
  const float* adj  = (const float*)d_in[1];
  const float* W1   = (const float*)d_in[3];
  const float* b1   = (const float*)d_in[4];
  const float* Watt = (const float*)d_in[5];
  const float* batt = (const float*)d_in[6];
  const float* W2   = (const float*)d_in[7];
  const float* b2   = (const float*)d_in[8];

  float* out = (float*)d_out;
  float* xs0   = out;                    // [8,128]
  float* xs1   = out + 1024;             // [8,256]
  float* oadj0 = out + 3072;             // [8,1024,1024] — Ct scratch until end
  float* oadj1 = oadj0 + 8388608;
  float* oadj2 = oadj1 + 8388608;        // adj_bf scratch until adj2 written
  float* oS0   = oadj2 + 8388608;
  float* oS1   = oS0 + 8388608;
  float* oloss = oS1 + 8388608;          // [1]

  float* ws   = (float*)d_ws;
  float* wXW  = ws;                       // 2,097,152
  float* wCXA = wXW + 2097152;            // 1,048,576  (x1, later emb2)
  float* wCXB = wCXA + 1048576;           // 1,048,576  (emb1)
  float* wR   = wCXB + 1048576;           // 8,388,608  (partials | tmp_bf | Cmat)
  float* wX2  = wR + 8388608;             // 2,097,152  (x2)
  float* wStf = wX2 + 2097152;            // 4,194,304  (St bf16; later x splits)
  float* wCxtf= wStf + 4194304;           // 524,288    (cxt bf16)
  float* smb  = wCxtf + 524288;
  unsigned short* tmp_bf = (unsigned short*)wR;        // 8.4M bf16 (first half)
  unsigned short* adj_bf = (unsigned short*)oadj2;     // 8.4M bf16 (16.7MB of 33.5)
  unsigned short* St     = (unsigned short*)wStf;
  unsigned short* cxt    = (unsigned short*)wCxtf;
  unsigned short* xh  = (unsigned short*)wStf;         // after St dead
  unsigned short* xl  = xh + 2097152;
  unsigned short* x2h = xh + 4194304;
  unsigned short* x2l = xh + 6291456;
  float* Cmat = wR;
  float* Ct   = oadj0;
  float* d0 = smb;            float* rm0 = smb + 8192;
  float* d1 = smb + 16384;    float* rm1 = smb + 24576;
  float* d2 = smb + 32768;    float* rm2 = smb + 40960;
  float* s0v = smb + 49152;   float* alp = smb + 57344;
  float* xxv = smb + 65536;   float* yyv = smb + 73728;
  float* uv  = smb + 81920;   float* vv  = smb + 90112;
  float* cutv = smb + 98304;  float* part = smb + 98368;

  // rowstats on adj + fused fp32->bf16 copy (adj_bf in oadj2 region)
  k_rowstats4<1><<<2048, 256, 0, stream>>>(adj, d0, rm0, adj_bf);

  // ---- first GCN layer (fp32, K-split): x1 = relu(norm(adj)@(x@W1) + b1) ----
  k_gemm_ks<0><<<dim3(1, 64, 2), 256, 0, stream>>>(x, W1, wR, 8192, HIDN, FIN, 2,
      0L, 0L, nullptr);
  k_red_bias<0,0><<<1024, 256, 0, stream>>>(wR, nullptr, wXW, HIDN, 2, 1048576L);
  k_gemm_ks<1><<<dim3(1, 8, 64), 256, 0, stream>>>(adj, wXW, wR, 1024, HIDN, 1024, 8,
      1048576L, 131072L, d0);
  k_red_bias<1,1><<<1024, 256, 0, stream>>>(wR, b1, wCXA, HIDN, 8, 131072L);
  k_colmean<<<16, 256, 0, stream>>>(wCXA, HIDN, xs0);

  // ---- coarsen layer 1 ----
  k_rowdot<<<2048, 256, 0, stream>>>(wCXA, Watt, s0v);
  k_alpha4<<<2048, 256, 0, stream>>>(adj, d0, s0v, batt, alp);
  k_topk<<<8, 512, 0, stream>>>(alp, cutv);
  k_sbuild4<<<2048, 256, 0, stream>>>(adj, d0, rm0, alp, cutv, oS0);
  k_transp<<<dim3(16, 16, 8), 256, 0, stream>>>(oS0, St, 1024, 1024);
  k_transp<<<dim3(2, 16, 8), 256, 0, stream>>>(wCXA, cxt, 1024, 128);
  k_mfma_nt<1,0><<<dim3(1, 8, 8), 256, 0, stream>>>(St, cxt, wCXB, nullptr,
      1024, 1024, 1024, 128, 1048576L, 131072L, 131072L);
  k_mfma_nt<0,1><<<dim3(8, 8, 8), 256, 0, stream>>>(St, adj_bf, nullptr, tmp_bf,
      1024, 1024, 1024, 1024, 1048576L, 1048576L, 1048576L);
  k_mfma_nt<1,1><<<dim3(8, 8, 8), 256, 0, stream>>>(tmp_bf, St, oadj1, adj_bf,
      1024, 1024, 1024, 1024, 1048576L, 1048576L, 1048576L);
  k_rowstats4<0><<<2048, 256, 0, stream>>>(oadj1, d1, rm1, nullptr);

  // ---- coarsen layer 2 ----
  k_rowdot<<<2048, 256, 0, stream>>>(wCXB, Watt, s0v);
  k_alpha4<<<2048, 256, 0, stream>>>(oadj1, d1, s0v, batt, alp);
  k_topk<<<8, 512, 0, stream>>>(alp, cutv);
  k_sbuild4<<<2048, 256, 0, stream>>>(oadj1, d1, rm1, alp, cutv, oS1);
  k_transp<<<dim3(16, 16, 8), 256, 0, stream>>>(oS1, St, 1024, 1024);
  k_transp<<<dim3(2, 16, 8), 256, 0, stream>>>(wCXB, cxt, 1024, 128);
  k_mfma_nt<1,0><<<dim3(1, 8, 8), 256, 0, stream>>>(St, cxt, wCXA, nullptr,
      1024, 1024, 1024, 128, 1048576L, 131072L, 131072L);
  k_mfma_nt<0,1><<<dim3(8, 8, 8), 256, 0, stream>>>(St, adj_bf, nullptr, tmp_bf,
      1024, 1024, 1024, 1024, 1048576L, 1048576L, 1048576L);
  k_mfma_nt<1,0><<<dim3(8, 8, 8), 256, 0, stream>>>(tmp_bf, St, oadj2, nullptr,
      1024, 1024, 1024, 1024, 1048576L, 1048576L, 1048576L);
  k_rowstats4<0><<<2048, 256, 0, stream>>>(oadj2, d2, rm2, nullptr);

  // ---- final GCN (fp32, K-split): x2 = norm(adj2)@(emb2@W2) + b2 ----
  k_gemm<0,0,0,0><<<dim3(2, 64, 1), 256, 0, stream>>>(wCXA, W2, wXW, 8192, FIN, HIDN,
      0L, 0L, 0L, nullptr, nullptr, 0, nullptr, nullptr);
  k_gemm_ks<1><<<dim3(2, 8, 32), 256, 0, stream>>>(oadj2, wXW, wR, 1024, FIN, 1024, 4,
      1048576L, 262144L, d2);
  k_red_bias<0,1><<<2048, 256, 0, stream>>>(wR, b2, wX2, FIN, 4, 262144L);
  k_colmean<<<32, 256, 0, stream>>>(wX2, FIN, xs1);

  // ---- Sinkhorn: C via split-bf16 MFMA Gram; C in wR, C^T in oadj0 ----
  k_sqnorm<<<2048, 256, 0, stream>>>(x, FIN, xxv);
  k_sqnorm<<<2048, 256, 0, stream>>>(wX2, FIN, yyv);
  k_split2<<<2048, 256, 0, stream>>>(x, xh, xl);
  k_split2<<<2048, 256, 0, stream>>>(wX2, x2h, x2l);
  k_mfma_gram<<<dim3(8, 8, 8), 256, 0, stream>>>(xh, xl, x2h, x2l, xxv, yyv, Cmat);
  k_transpf<<<dim3(16, 16, 8), 256, 0, stream>>>(Cmat, Ct);
  hipMemsetAsync(uv, 0, (size_t)2 * 8192 * 4, stream);
  for (int it = 0; it < NITER; ++it) {
    k_sink8<0><<<1024, 256, 0, stream>>>(Cmat, vv, uv, nullptr);
    if (it < NITER - 1)
      k_sink8<0><<<1024, 256, 0, stream>>>(Ct, uv, vv, nullptr);
    else
      k_sink8<1><<<1024, 256, 0, stream>>>(Ct, uv, vv, part);  // fused loss
  }
  k_psum<<<1, 256, 0, stream>>>(part, oloss);

  // new_adjs[0] = adj (after Ct scratch in oadj0 is dead)
  hipMemcpyAsync(oadj0, adj, (size_t)8388608 * 4, hipMemcpyDeviceToDevice, stream);
}